// Round 6
// baseline (346.169 us; speedup 1.0000x reference)
//
#include <hip/hip_runtime.h>
#include <math.h>

#define NB 64
#define KK 512
#define ND 1024
#define NH 32
#define G3 96   // 3*H
#define DPE 32

typedef float v2f __attribute__((ext_vector_type(2)));

// xor-shuffle across lanes: ds_swizzle (imm pattern) for m<=16, shfl for 32.
__device__ __forceinline__ float swz_xor(float x, const int m) {
  if (m == 32) return __shfl_xor(x, 32, 64);
  int xi = __float_as_int(x), r;
  if (m == 1)       r = __builtin_amdgcn_ds_swizzle(xi, 0x041F);
  else if (m == 2)  r = __builtin_amdgcn_ds_swizzle(xi, 0x081F);
  else if (m == 4)  r = __builtin_amdgcn_ds_swizzle(xi, 0x101F);
  else if (m == 8)  r = __builtin_amdgcn_ds_swizzle(xi, 0x201F);
  else              r = __builtin_amdgcn_ds_swizzle(xi, 0x401F);  // m == 16
  return __int_as_float(r);
}

__device__ __forceinline__ float rdl(float v, int i) {
  return __uint_as_float(__builtin_amdgcn_readlane(__float_as_uint(v), i));
}

// ---------------- kernel 1: x-projection (pe @ kernel + bias0 + zr-part of
// bias1 folded), both dirs ----------------------------------------------------
__global__ __launch_bounds__(192) void xproj_kernel(
    const float* __restrict__ kF, const float* __restrict__ bF,
    const float* __restrict__ kB, const float* __restrict__ bB,
    float* __restrict__ xproj) {
  int k = blockIdx.x;
  int t = threadIdx.x;
  __shared__ float pe[DPE];
  if (t < DPE) {
    int j = t >> 1;
    float dv = expf((float)j * -0.57564627324851147f);  // -ln(10000)/16
    float arg = (float)k * dv;
    pe[t] = (t & 1) ? cosf(arg) : sinf(arg);
  }
  __syncthreads();
  int dir = t / G3;
  int c = t - dir * G3;
  const float* kern = dir ? kB : kF;
  const float* bias = dir ? bB : bF;
  float acc = bias[c] + (c < 64 ? bias[G3 + c] : 0.f);  // fold recurrent zr bias
#pragma unroll
  for (int i = 0; i < DPE; ++i) acc = fmaf(pe[i], kern[i * G3 + c], acc);
  xproj[dir * (KK * G3) + k * G3 + c] = acc;
}

// ---------------- kernel 2: dual-direction GRU, 1 wave per batch ------------
// fwd and bwd recurrences interleaved in one instruction stream so each
// chain's latency bubbles (readlane/exp/rcp) are filled by the other chain.
// h histories in 128KB LDS; score + softmax fused into the tail.
#if __has_builtin(__builtin_amdgcn_permlane32_swap)
#define PLSWAP(sig, z, r) { auto pr_ = __builtin_amdgcn_permlane32_swap(       \
      __float_as_uint(sig), __float_as_uint(sig), false, false);               \
    z = __uint_as_float(pr_[0]); r = __uint_as_float(pr_[1]); }
#else
#define PLSWAP(sig, z, r) { float o_ = __shfl_xor(sig, 32, 64);                \
    bool mz_ = (zrcol < 32); z = mz_ ? sig : o_; r = mz_ ? o_ : sig; }
#endif

#define GRU_STEP(hval, rk2, bh, xzrv, xhv, histp, prow)                        \
  {                                                                            \
    v2f a0 = {0.f,0.f}, a1 = {0.f,0.f}, a2 = {0.f,0.f}, a3 = {0.f,0.f};        \
    _Pragma("unroll")                                                          \
    for (int i = 0; i < 32; i += 4) {                                          \
      float h0 = rdl(hval, i), h1 = rdl(hval, i+1),                            \
            h2 = rdl(hval, i+2), h3 = rdl(hval, i+3);                          \
      a0 = __builtin_elementwise_fma((v2f){h0,h0}, rk2[i+0], a0);              \
      a1 = __builtin_elementwise_fma((v2f){h1,h1}, rk2[i+1], a1);              \
      a2 = __builtin_elementwise_fma((v2f){h2,h2}, rk2[i+2], a2);              \
      a3 = __builtin_elementwise_fma((v2f){h3,h3}, rk2[i+3], a3);              \
    }                                                                          \
    v2f asum = (a0 + a1) + (a2 + a3);                                          \
    float zr_pre = asum.x + (xzrv);                                            \
    float hh = asum.y + (bh);                                                  \
    float sig = __builtin_amdgcn_rcpf(1.f + __expf(-zr_pre));                  \
    float z, r;                                                                \
    PLSWAP(sig, z, r);                                                         \
    float pre = fmaf(r, hh, (xhv));                                            \
    float e2 = __expf(2.f * pre);                                              \
    float hc = fmaf(-2.f, __builtin_amdgcn_rcpf(e2 + 1.f), 1.f);               \
    hval = fmaf(z, hval - hc, hc);                                             \
    if (l < 32) (histp)[(prow) * NH + (c ^ ((prow) & 31))] = hval;             \
  }

__global__ __launch_bounds__(64, 1) void gru6_kernel(
    const float* __restrict__ rkF, const float* __restrict__ rkB,
    const float* __restrict__ bF, const float* __restrict__ bB,
    const float* __restrict__ lw, const int* __restrict__ lengths,
    const float* __restrict__ xproj, float* __restrict__ wts,
    float* __restrict__ outW) {
  __shared__ float hist[2 * KK * NH];  // 128 KB: [dir][k][c], c XOR-swizzled
  float* histA = hist;
  float* histB = hist + KK * NH;
  int b = blockIdx.x;
  int l = threadIdx.x;
  int c = l & 31;
  int len = lengths[b];

#if __has_builtin(__builtin_amdgcn_permlane32_swap)
  auto chk = __builtin_amdgcn_permlane32_swap(
      __float_as_uint(l < 32 ? 1.f : 2.f), __float_as_uint(l < 32 ? 1.f : 2.f),
      false, false);
  bool xIsLo = (__uint_as_float(chk[0]) == 1.f);
#else
  bool xIsLo = true;
#endif
  int zrcol = (xIsLo == (l < 32)) ? c : (32 + c);

  v2f rkA[32], rkB2[32];  // .x: zr coefficient, .y: h coefficient
#pragma unroll
  for (int i = 0; i < 32; ++i) {
    rkA[i]  = (v2f){rkF[i * G3 + zrcol], rkF[i * G3 + 64 + c]};
    rkB2[i] = (v2f){rkB[i * G3 + zrcol], rkB[i * G3 + 64 + c]};
  }
  float bhA = bF[G3 + 64 + c];
  float bhB = bB[G3 + 64 + c];

  const float* xpA = xproj;                 // fwd: rows 0..len-1
  const float* xpB = xproj + KK * G3;       // bwd: rows len-1..0

  // 8-deep prefetch rings for both chains (len >= 256 so initial rows valid)
  float xzrA[8], xhA[8], xzrB[8], xhB[8];
#pragma unroll
  for (int j = 0; j < 8; ++j) {
    const float* ra = xpA + (size_t)j * G3;
    const float* rb = xpB + (size_t)(len - 1 - j) * G3;
    xzrA[j] = ra[zrcol]; xhA[j] = ra[64 + c];
    xzrB[j] = rb[zrcol]; xhB[j] = rb[64 + c];
  }

  float hA = 0.f, hB = 0.f;
  for (int s0 = 0; s0 < len; s0 += 8) {
#pragma unroll
    for (int j = 0; j < 8; ++j) {
      int s = s0 + j;
      if (s < len) {
        int pA = s, pB = len - 1 - s;
        GRU_STEP(hA, rkA, bhA, xzrA[j], xhA[j], histA, pA);
        GRU_STEP(hB, rkB2, bhB, xzrB[j], xhB[j], histB, pB);
        int pn = s + 8; pn = pn > len - 1 ? len - 1 : pn;
        const float* ra = xpA + (size_t)pn * G3;
        const float* rb = xpB + (size_t)(len - 1 - pn) * G3;
        xzrA[j] = ra[zrcol]; xhA[j] = ra[64 + c];
        xzrB[j] = rb[zrcol]; xhB[j] = rb[64 + c];
      }
    }
  }
  __syncthreads();

  // tail: scores for all k in parallel, then in-block softmax
  float lwA[NH], lwB[NH];
#pragma unroll
  for (int i = 0; i < NH; ++i) { lwA[i] = lw[i]; lwB[i] = lw[NH + i]; }
  float sc[8];
#pragma unroll
  for (int it = 0; it < 8; ++it) {
    int k = it * 64 + l;
    float a = -10000.f;
    if (k < len) {
      float accA = 0.f, accB = 0.f;
#pragma unroll
      for (int i = 0; i < NH; ++i) {
        accA = fmaf(histA[k * NH + (i ^ (k & 31))], lwA[i], accA);
        accB = fmaf(histB[k * NH + (i ^ (k & 31))], lwB[i], accB);
      }
      a = accA + accB;
    }
    sc[it] = a;
  }
  float mx = sc[0];
#pragma unroll
  for (int it = 1; it < 8; ++it) mx = fmaxf(mx, sc[it]);
#pragma unroll
  for (int m = 1; m <= 16; m <<= 1) mx = fmaxf(mx, swz_xor(mx, m));
  mx = fmaxf(mx, __shfl_xor(mx, 32, 64));
  float e[8], sum = 0.f;
#pragma unroll
  for (int it = 0; it < 8; ++it) { e[it] = __expf((sc[it] - mx) * 10.f); sum += e[it]; }
#pragma unroll
  for (int m = 1; m <= 16; m <<= 1) sum += swz_xor(sum, m);
  sum += __shfl_xor(sum, 32, 64);
  float inv = 1.f / sum;
#pragma unroll
  for (int it = 0; it < 8; ++it) {
    int k = it * 64 + l;
    float w = e[it] * inv;
    wts[b * KK + k] = w;
    outW[b * KK + k] = w;
  }
}

// ---------------- kernel 3: per-(b,d) descending sort + weighted pool -------
// grid: 64 b x 128 dtiles (8 cols). Wave sorts 2 columns (512 = 64 lanes x 8
// regs, s = 8*lane + r) with sign-flip "prime domain" bitonic: in-reg CE =
// min+max only; cross-lane CE = ds_swizzle + min + max + cndmask(hb).
#define CEA(a, b) { float lo_ = fminf(a, b), hi_ = fmaxf(a, b); a = lo_; b = hi_; }
#define CED(a, b) { float lo_ = fminf(a, b), hi_ = fmaxf(a, b); a = hi_; b = lo_; }

__global__ __launch_bounds__(256, 6) void sortpool_kernel(
    const float* __restrict__ feat, const int* __restrict__ lengths,
    const float* __restrict__ wts, float* __restrict__ outP) {
  __shared__ float tile[KK * 9];    // 18 KB, pad-9 rows, rotation-swizzled
  __shared__ float wperm[KK];       // transposed weight layout
  int bid = blockIdx.x;
  int b = bid >> 7;
  int dt = bid & 127;
  int d0 = dt * 8;
  int t = threadIdx.x;
  int len = lengths[b];

  // stage weights (w[i] at (i&7)*64 + (i>>3) -> conflict-free read)
#pragma unroll
  for (int it = 0; it < 2; ++it) {
    int i = it * 256 + t;
    wperm[(i & 7) * 64 + (i >> 3)] = wts[b * KK + i];
  }
  // stage features: float4 global reads, swizzled LDS writes (col' = col+rot mod 8)
  const float4* g = reinterpret_cast<const float4*>(feat + (size_t)b * KK * ND + d0);
  int c4 = t & 1, kb = t >> 1;
#pragma unroll
  for (int it = 0; it < 4; ++it) {
    int k = it * 128 + kb;
    float4 vv = g[(size_t)k * 256 + c4];
    if (k >= len) { vv.x = -10000.f; vv.y = -10000.f; vv.z = -10000.f; vv.w = -10000.f; }
    int base = k * 9;
    int rot = k >> 5;
    tile[base + ((c4 * 4 + 0 + rot) & 7)] = vv.x;
    tile[base + ((c4 * 4 + 1 + rot) & 7)] = vv.y;
    tile[base + ((c4 * 4 + 2 + rot) & 7)] = vv.z;
    tile[base + ((c4 * 4 + 3 + rot) & 7)] = vv.w;
  }
  __syncthreads();

  int wv = t >> 6, l = t & 63;
  // load this wave's 2 columns into registers
  float v[2][8];
#pragma unroll
  for (int cc = 0; cc < 2; ++cc) {
    int dd = wv * 2 + cc;
#pragma unroll
    for (int r = 0; r < 8; ++r) {
      int k = 8 * l + r;
      v[cc][r] = tile[k * 9 + ((dd + (l >> 2)) & 7)];
    }
  }

  // ---- kk=1,2 (directions compile-time in r) ----
#pragma unroll
  for (int cc = 0; cc < 2; ++cc) {
    CEA(v[cc][0], v[cc][1]); CED(v[cc][2], v[cc][3]);
    CEA(v[cc][4], v[cc][5]); CED(v[cc][6], v[cc][7]);
    CEA(v[cc][0], v[cc][2]); CEA(v[cc][1], v[cc][3]);
    CED(v[cc][4], v[cc][6]); CED(v[cc][5], v[cc][7]);
    CEA(v[cc][0], v[cc][1]); CEA(v[cc][2], v[cc][3]);
    CED(v[cc][4], v[cc][5]); CED(v[cc][6], v[cc][7]);
  }
  // ---- enter prime domain for kk=3: flip descending lanes' sign ----
  {
    int S = (l & 1) << 31;
#pragma unroll
    for (int cc = 0; cc < 2; ++cc)
#pragma unroll
      for (int r = 0; r < 8; ++r)
        v[cc][r] = __int_as_float(__float_as_int(v[cc][r]) ^ S);
  }
  // kk=3: all in-reg, ascending in prime domain
#pragma unroll
  for (int cc = 0; cc < 2; ++cc) {
    CEA(v[cc][0], v[cc][4]); CEA(v[cc][1], v[cc][5]); CEA(v[cc][2], v[cc][6]); CEA(v[cc][3], v[cc][7]);
    CEA(v[cc][0], v[cc][2]); CEA(v[cc][1], v[cc][3]); CEA(v[cc][4], v[cc][6]); CEA(v[cc][5], v[cc][7]);
    CEA(v[cc][0], v[cc][1]); CEA(v[cc][2], v[cc][3]); CEA(v[cc][4], v[cc][5]); CEA(v[cc][6], v[cc][7]);
  }
  // ---- kk = 4..9 merge stages ----
#pragma unroll
  for (int kk = 4; kk <= 9; ++kk) {
    // re-flip into stage kk's prime domain
    int dS = (((l >> (kk - 4)) ^ (l >> (kk - 3))) & 1) << 31;
#pragma unroll
    for (int cc = 0; cc < 2; ++cc)
#pragma unroll
      for (int r = 0; r < 8; ++r)
        v[cc][r] = __int_as_float(__float_as_int(v[cc][r]) ^ dS);
    // cross-lane substages: keepmin' = !hb, uniform across stages
#pragma unroll
    for (int j = kk - 1; j >= 3; --j) {
      const int m = 1 << (j - 3);
      bool hb = ((l >> (j - 3)) & 1) != 0;
#pragma unroll
      for (int cc = 0; cc < 2; ++cc)
#pragma unroll
        for (int r = 0; r < 8; ++r) {
          float p = swz_xor(v[cc][r], m);
          float mn = fminf(v[cc][r], p), mx2 = fmaxf(v[cc][r], p);
          v[cc][r] = hb ? mx2 : mn;
        }
    }
    // in-reg substages j=2,1,0: ascending in prime domain
#pragma unroll
    for (int cc = 0; cc < 2; ++cc) {
      CEA(v[cc][0], v[cc][4]); CEA(v[cc][1], v[cc][5]); CEA(v[cc][2], v[cc][6]); CEA(v[cc][3], v[cc][7]);
      CEA(v[cc][0], v[cc][2]); CEA(v[cc][1], v[cc][3]); CEA(v[cc][4], v[cc][6]); CEA(v[cc][5], v[cc][7]);
      CEA(v[cc][0], v[cc][1]); CEA(v[cc][2], v[cc][3]); CEA(v[cc][4], v[cc][5]); CEA(v[cc][6], v[cc][7]);
    }
  }
  // S_9 == 0 for all lanes (l < 64): already back in plain domain, ascending.

  // weighted sum: ascending rank s=8l+r -> descending rank jd = 511-s.
  // wts[jd] == 0 exactly for jd >= len, so no guard needed.
  float acc0 = 0.f, acc1 = 0.f;
#pragma unroll
  for (int r = 0; r < 8; ++r) {
    float w = wperm[((7 - r) & 7) * 64 + (63 - l)];
    acc0 = fmaf(v[0][r], w, acc0);
    acc1 = fmaf(v[1][r], w, acc1);
  }
#pragma unroll
  for (int m = 1; m <= 16; m <<= 1) {
    acc0 += swz_xor(acc0, m);
    acc1 += swz_xor(acc1, m);
  }
  acc0 += __shfl_xor(acc0, 32, 64);
  acc1 += __shfl_xor(acc1, 32, 64);
  if (l == 0) {
    outP[(size_t)b * ND + d0 + wv * 2 + 0] = acc0;
    outP[(size_t)b * ND + d0 + wv * 2 + 1] = acc1;
  }
}

extern "C" void kernel_launch(void* const* d_in, const int* in_sizes, int n_in,
                              void* d_out, int out_size, void* d_ws, size_t ws_size,
                              hipStream_t stream) {
  const float* feat    = (const float*)d_in[0];
  const int*   lengths = (const int*)d_in[1];
  const float* kF      = (const float*)d_in[2];
  const float* rkF     = (const float*)d_in[3];
  const float* bF      = (const float*)d_in[4];
  const float* kB      = (const float*)d_in[5];
  const float* rkB     = (const float*)d_in[6];
  const float* bB      = (const float*)d_in[7];
  const float* lw      = (const float*)d_in[8];

  float* outP = (float*)d_out;                 // pooled [64,1024]
  float* outW = (float*)d_out + NB * ND;       // weights [64,512]

  float* ws    = (float*)d_ws;
  float* xproj = ws;                           // [2][512][96]
  float* wts   = ws + 2 * KK * G3;             // [64][512]

  xproj_kernel<<<KK, 192, 0, stream>>>(kF, bF, kB, bB, xproj);
  gru6_kernel<<<NB, 64, 0, stream>>>(rkF, rkB, bF, bB, lw, lengths, xproj, wts, outW);
  sortpool_kernel<<<NB * 128, 256, 0, stream>>>(feat, lengths, wts, outP);
}

// Round 7
// 265.994 us; speedup vs baseline: 1.3014x; 1.3014x over previous
//
#include <hip/hip_runtime.h>
#include <math.h>

#define NB 64
#define KK 512
#define ND 1024
#define NH 32
#define G3 96   // 3*H
#define DPE 32

typedef float v2f __attribute__((ext_vector_type(2)));

// xor-shuffle across lanes: ds_swizzle (imm pattern) for m<=16.
__device__ __forceinline__ float swz_xor(float x, const int m) {
  int xi = __float_as_int(x), r;
  if (m == 1)       r = __builtin_amdgcn_ds_swizzle(xi, 0x041F);
  else if (m == 2)  r = __builtin_amdgcn_ds_swizzle(xi, 0x081F);
  else if (m == 4)  r = __builtin_amdgcn_ds_swizzle(xi, 0x101F);
  else if (m == 8)  r = __builtin_amdgcn_ds_swizzle(xi, 0x201F);
  else              r = __builtin_amdgcn_ds_swizzle(xi, 0x401F);  // m == 16
  return __int_as_float(r);
}

__device__ __forceinline__ float rdl(float v, int i) {
  return __uint_as_float(__builtin_amdgcn_readlane(__float_as_uint(v), i));
}

// ---------------- kernel 1: x-projection (pe @ kernel + bias0 + zr-part of
// bias1 folded), both dirs ----------------------------------------------------
__global__ __launch_bounds__(192) void xproj_kernel(
    const float* __restrict__ kF, const float* __restrict__ bF,
    const float* __restrict__ kB, const float* __restrict__ bB,
    float* __restrict__ xproj) {
  int k = blockIdx.x;
  int t = threadIdx.x;
  __shared__ float pe[DPE];
  if (t < DPE) {
    int j = t >> 1;
    float dv = expf((float)j * -0.57564627324851147f);  // -ln(10000)/16
    float arg = (float)k * dv;
    pe[t] = (t & 1) ? cosf(arg) : sinf(arg);
  }
  __syncthreads();
  int dir = t / G3;
  int c = t - dir * G3;
  const float* kern = dir ? kB : kF;
  const float* bias = dir ? bB : bF;
  float acc = bias[c] + (c < 64 ? bias[G3 + c] : 0.f);  // fold recurrent zr bias
#pragma unroll
  for (int i = 0; i < DPE; ++i) acc = fmaf(pe[i], kern[i * G3 + c], acc);
  xproj[dir * (KK * G3) + k * G3 + c] = acc;
}

// ---------------- kernel 2: sequential GRU, 1 wave per (b,dir) --------------
// launch_bounds(64,1): full VGPR budget, recurrent weights register-resident.
// 8-deep register ring for xproj prefetch. All 32 readlanes hoisted BEFORE the
// FMA block: v_readlane writes its SGPR >=32 instrs before the first read, so
// the VALU->SGPR-read hazard wait-states are filled with useful readlanes.
__global__ __launch_bounds__(64, 1) void gru5_kernel(
    const float* __restrict__ rkF, const float* __restrict__ rkB,
    const float* __restrict__ bF, const float* __restrict__ bB,
    const float* __restrict__ lw, const int* __restrict__ lengths,
    const float* __restrict__ xproj, float* __restrict__ scoreW) {
  __shared__ float hist[KK * NH];  // 64 KB, element (k,c) at k*32 + (c^(k&31))
  int bid = blockIdx.x;
  int b = bid >> 1, dir = bid & 1;
  int l = threadIdx.x;
  int c = l & 31;
  const float* rk_g = dir ? rkB : rkF;
  const float* bias = dir ? bB : bF;
  const float* xp_g = xproj + dir * (KK * G3);
  int len = lengths[b];

#if __has_builtin(__builtin_amdgcn_permlane32_swap)
  auto chk = __builtin_amdgcn_permlane32_swap(
      __float_as_uint(l < 32 ? 1.f : 2.f), __float_as_uint(l < 32 ? 1.f : 2.f),
      false, false);
  bool xIsLo = (__uint_as_float(chk[0]) == 1.f);
#else
  bool xIsLo = true;
#endif
  // Column assignment so that swap-result[0] is always z, result[1] always r.
  int zrcol = (xIsLo == (l < 32)) ? c : (32 + c);

  v2f rk2[32];  // .x: zr-column coefficient, .y: h-column coefficient
#pragma unroll
  for (int i = 0; i < 32; ++i) {
    rk2[i] = (v2f){rk_g[i * G3 + zrcol], rk_g[i * G3 + 64 + c]};
  }
  float b_h = bias[G3 + 64 + c];

  // prefetch ring, depth 8 (static indices via full unroll)
  float xzr[8], xh[8];
#pragma unroll
  for (int j = 0; j < 8; ++j) {
    int pn = dir ? (len - 1 - j) : j;
    pn = pn < 0 ? 0 : (pn > len - 1 ? len - 1 : pn);
    const float* rp = xp_g + (size_t)pn * G3;
    xzr[j] = rp[zrcol];
    xh[j] = rp[64 + c];
  }

  float hval = 0.f;
  for (int s0 = 0; s0 < len; s0 += 8) {
#pragma unroll
    for (int j = 0; j < 8; ++j) {
      int s = s0 + j;
      if (s < len) {
        // batch all readlanes first (hazard-filling), then the FMA block
        float hs[32];
#pragma unroll
        for (int i = 0; i < 32; ++i) hs[i] = rdl(hval, i);
        v2f a0 = {0.f, 0.f}, a1 = {0.f, 0.f}, a2 = {0.f, 0.f}, a3 = {0.f, 0.f};
#pragma unroll
        for (int i = 0; i < 32; i += 4) {
          a0 = __builtin_elementwise_fma((v2f){hs[i + 0], hs[i + 0]}, rk2[i + 0], a0);
          a1 = __builtin_elementwise_fma((v2f){hs[i + 1], hs[i + 1]}, rk2[i + 1], a1);
          a2 = __builtin_elementwise_fma((v2f){hs[i + 2], hs[i + 2]}, rk2[i + 2], a2);
          a3 = __builtin_elementwise_fma((v2f){hs[i + 3], hs[i + 3]}, rk2[i + 3], a3);
        }
        v2f asum = (a0 + a1) + (a2 + a3);
        float zr_pre = asum.x + xzr[j];                 // bias folded into xproj
        float hh = asum.y + b_h;
        float sig = __builtin_amdgcn_rcpf(1.f + __expf(-zr_pre));
#if __has_builtin(__builtin_amdgcn_permlane32_swap)
        auto pr = __builtin_amdgcn_permlane32_swap(__float_as_uint(sig),
                                                   __float_as_uint(sig), false, false);
        float z = __uint_as_float(pr[0]);
        float r = __uint_as_float(pr[1]);
#else
        float other = __shfl_xor(sig, 32, 64);
        bool mineIsZ = (zrcol < 32);
        float z = mineIsZ ? sig : other;
        float r = mineIsZ ? other : sig;
#endif
        float pre = fmaf(r, hh, xh[j]);
        float e2 = __expf(2.f * pre);                   // tanh = 1 - 2/(e2+1)
        float hc = fmaf(-2.f, __builtin_amdgcn_rcpf(e2 + 1.f), 1.f);
        hval = fmaf(z, hval - hc, hc);
        int p = dir ? (len - 1 - s) : s;
        if (l < 32) hist[p * NH + (c ^ (p & 31))] = hval;  // conflict-free
        // prefetch step s+8 into this ring slot (clamped row; off critical path)
        int pn = dir ? (len - 1 - (s + 8)) : (s + 8);
        pn = pn < 0 ? 0 : (pn > len - 1 ? len - 1 : pn);
        const float* rp = xp_g + (size_t)pn * G3;
        xzr[j] = rp[zrcol];
        xh[j] = rp[64 + c];
      }
    }
  }
  __syncthreads();

  // tail: scores for all k in parallel (lane l handles k = it*64 + l)
  float lws[NH];
#pragma unroll
  for (int i = 0; i < NH; ++i) lws[i] = lw[dir * NH + i];
  float* so = scoreW + (size_t)(dir * NB + b) * KK;
#pragma unroll
  for (int it = 0; it < 8; ++it) {
    int k = it * 64 + l;
    if (k < len) {
      float acc = 0.f;
#pragma unroll
      for (int i = 0; i < NH; ++i)
        acc = fmaf(hist[k * NH + (i ^ (k & 31))], lws[i], acc);
      so[k] = acc;
    }
  }
}

// ---------------- kernel 3: softmax over K per batch ------------------------
__global__ __launch_bounds__(256) void softmax_kernel(
    const int* __restrict__ lengths, const float* __restrict__ scoreW,
    float* __restrict__ wts, float* __restrict__ outW) {
  int b = blockIdx.x;
  int t = threadIdx.x;
  int len = lengths[b];
  const float* sf = scoreW + b * KK;
  const float* sb = scoreW + (NB + b) * KK;
  int k0 = t, k1 = t + 256;
  float s0 = -10000.f, s1 = -10000.f;
  if (k0 < len) s0 = sf[k0] + sb[k0];
  if (k1 < len) s1 = sf[k1] + sb[k1];
  float mx = fmaxf(s0, s1);
#pragma unroll
  for (int m = 32; m >= 1; m >>= 1) mx = fmaxf(mx, __shfl_xor(mx, m, 64));
  __shared__ float redm[4];
  __shared__ float reds[4];
  int wid = t >> 6, lane = t & 63;
  if (lane == 0) redm[wid] = mx;
  __syncthreads();
  mx = fmaxf(fmaxf(redm[0], redm[1]), fmaxf(redm[2], redm[3]));
  float e0 = expf((s0 - mx) * 10.f);  // padded -> exp(~-1e5) == 0 exactly
  float e1 = expf((s1 - mx) * 10.f);
  float sum = e0 + e1;
#pragma unroll
  for (int m = 32; m >= 1; m >>= 1) sum += __shfl_xor(sum, m, 64);
  if (lane == 0) reds[wid] = sum;
  __syncthreads();
  sum = (reds[0] + reds[1]) + (reds[2] + reds[3]);
  float inv = 1.f / sum;
  float w0 = e0 * inv, w1 = e1 * inv;
  wts[b * KK + k0] = w0;
  wts[b * KK + k1] = w1;
  outW[b * KK + k0] = w0;
  outW[b * KK + k1] = w1;
}

// ---------------- kernel 4: per-(b,d) descending sort + weighted pool -------
// grid: 64 b x 64 dtiles (16 cols, 64B-aligned fetch). 512 threads = 8 waves,
// 2 cols/wave. Prime-domain bitonic: in-reg CE = min+max; cross-lane CE =
// ds_swizzle+min+max+cndmask; dist-32 CE via permlane32_swap (VALU pipe,
// order-agnostic since min/max are symmetric in the two returns).
#define CEA(a, b) { float lo_ = fminf(a, b), hi_ = fmaxf(a, b); a = lo_; b = hi_; }
#define CED(a, b) { float lo_ = fminf(a, b), hi_ = fmaxf(a, b); a = hi_; b = lo_; }

__global__ __launch_bounds__(512, 8) void sortpool_kernel(
    const float* __restrict__ feat, const int* __restrict__ lengths,
    const float* __restrict__ wts, float* __restrict__ outP) {
  __shared__ float tile[KK * 16];   // 32 KB, rotation-swizzled
  __shared__ float wperm[KK];       // transposed weight layout
  int bid = blockIdx.x;
  int b = bid >> 6;
  int dt = bid & 63;
  int d0 = dt * 16;
  int t = threadIdx.x;
  int len = lengths[b];

  // stage weights (w[i] at (i&7)*64 + (i>>3) -> conflict-free read)
  if (t < KK) wperm[(t & 7) * 64 + (t >> 3)] = wts[b * KK + t];

  // stage features: 64B-aligned float4 reads, rotation-swizzled LDS writes
  const float4* g = reinterpret_cast<const float4*>(feat + (size_t)b * KK * ND + d0);
  int c4 = t & 3, kb = t >> 2;  // 4 float4-groups x 128 k-rows per iter
#pragma unroll
  for (int it = 0; it < 4; ++it) {
    int k = it * 128 + kb;
    float4 vv = g[(size_t)k * 256 + c4];
    if (k >= len) { vv.x = -10000.f; vv.y = -10000.f; vv.z = -10000.f; vv.w = -10000.f; }
    int base = k * 16;
    int rot = (k >> 3) + (k & 7);
    tile[base + ((c4 * 4 + 0 + rot) & 15)] = vv.x;
    tile[base + ((c4 * 4 + 1 + rot) & 15)] = vv.y;
    tile[base + ((c4 * 4 + 2 + rot) & 15)] = vv.z;
    tile[base + ((c4 * 4 + 3 + rot) & 15)] = vv.w;
  }
  __syncthreads();

  int wv = t >> 6, l = t & 63;
  // load this wave's 2 columns into registers (k = 8l + r -> rot = l + r)
  float v[2][8];
#pragma unroll
  for (int cc = 0; cc < 2; ++cc) {
    int dd = wv * 2 + cc;
#pragma unroll
    for (int r = 0; r < 8; ++r) {
      int k = 8 * l + r;
      v[cc][r] = tile[k * 16 + ((dd + l + r) & 15)];
    }
  }

  // ---- kk=1,2 (directions compile-time in r) ----
#pragma unroll
  for (int cc = 0; cc < 2; ++cc) {
    CEA(v[cc][0], v[cc][1]); CED(v[cc][2], v[cc][3]);
    CEA(v[cc][4], v[cc][5]); CED(v[cc][6], v[cc][7]);
    CEA(v[cc][0], v[cc][2]); CEA(v[cc][1], v[cc][3]);
    CED(v[cc][4], v[cc][6]); CED(v[cc][5], v[cc][7]);
    CEA(v[cc][0], v[cc][1]); CEA(v[cc][2], v[cc][3]);
    CED(v[cc][4], v[cc][5]); CED(v[cc][6], v[cc][7]);
  }
  // ---- enter prime domain for kk=3: flip descending lanes' sign ----
  {
    int S = (l & 1) << 31;
#pragma unroll
    for (int cc = 0; cc < 2; ++cc)
#pragma unroll
      for (int r = 0; r < 8; ++r)
        v[cc][r] = __int_as_float(__float_as_int(v[cc][r]) ^ S);
  }
  // kk=3: all in-reg, ascending in prime domain
#pragma unroll
  for (int cc = 0; cc < 2; ++cc) {
    CEA(v[cc][0], v[cc][4]); CEA(v[cc][1], v[cc][5]); CEA(v[cc][2], v[cc][6]); CEA(v[cc][3], v[cc][7]);
    CEA(v[cc][0], v[cc][2]); CEA(v[cc][1], v[cc][3]); CEA(v[cc][4], v[cc][6]); CEA(v[cc][5], v[cc][7]);
    CEA(v[cc][0], v[cc][1]); CEA(v[cc][2], v[cc][3]); CEA(v[cc][4], v[cc][5]); CEA(v[cc][6], v[cc][7]);
  }
  // ---- kk = 4..9 merge stages ----
#pragma unroll
  for (int kk = 4; kk <= 9; ++kk) {
    // re-flip into stage kk's prime domain
    int dS = (((l >> (kk - 4)) ^ (l >> (kk - 3))) & 1) << 31;
#pragma unroll
    for (int cc = 0; cc < 2; ++cc)
#pragma unroll
      for (int r = 0; r < 8; ++r)
        v[cc][r] = __int_as_float(__float_as_int(v[cc][r]) ^ dS);
    // cross-lane substages: keepmin' = !hb, uniform across stages
#pragma unroll
    for (int j = kk - 1; j >= 3; --j) {
      const int m = 1 << (j - 3);
      bool hb = ((l >> (j - 3)) & 1) != 0;
      if (m == 32) {
#if __has_builtin(__builtin_amdgcn_permlane32_swap)
#pragma unroll
        for (int cc = 0; cc < 2; ++cc)
#pragma unroll
          for (int r = 0; r < 8; ++r) {
            auto pr = __builtin_amdgcn_permlane32_swap(
                __float_as_uint(v[cc][r]), __float_as_uint(v[cc][r]), false, false);
            float u0 = __uint_as_float(pr[0]), u1 = __uint_as_float(pr[1]);
            v[cc][r] = hb ? fmaxf(u0, u1) : fminf(u0, u1);
          }
#else
#pragma unroll
        for (int cc = 0; cc < 2; ++cc)
#pragma unroll
          for (int r = 0; r < 8; ++r) {
            float p = __shfl_xor(v[cc][r], 32, 64);
            v[cc][r] = hb ? fmaxf(v[cc][r], p) : fminf(v[cc][r], p);
          }
#endif
      } else {
#pragma unroll
        for (int cc = 0; cc < 2; ++cc)
#pragma unroll
          for (int r = 0; r < 8; ++r) {
            float p = swz_xor(v[cc][r], m);
            float mn = fminf(v[cc][r], p), mx2 = fmaxf(v[cc][r], p);
            v[cc][r] = hb ? mx2 : mn;
          }
      }
    }
    // in-reg substages j=2,1,0: ascending in prime domain
#pragma unroll
    for (int cc = 0; cc < 2; ++cc) {
      CEA(v[cc][0], v[cc][4]); CEA(v[cc][1], v[cc][5]); CEA(v[cc][2], v[cc][6]); CEA(v[cc][3], v[cc][7]);
      CEA(v[cc][0], v[cc][2]); CEA(v[cc][1], v[cc][3]); CEA(v[cc][4], v[cc][6]); CEA(v[cc][5], v[cc][7]);
      CEA(v[cc][0], v[cc][1]); CEA(v[cc][2], v[cc][3]); CEA(v[cc][4], v[cc][5]); CEA(v[cc][6], v[cc][7]);
    }
  }
  // S_9 == 0 for all lanes (l < 64): back in plain domain, ascending.

  // weighted sum: ascending rank s=8l+r -> descending rank jd = 511-s.
  // wts[jd] == 0 exactly for jd >= len, so no guard needed.
  float acc0 = 0.f, acc1 = 0.f;
#pragma unroll
  for (int r = 0; r < 8; ++r) {
    float w = wperm[(7 - r) * 64 + (63 - l)];
    acc0 = fmaf(v[0][r], w, acc0);
    acc1 = fmaf(v[1][r], w, acc1);
  }
#pragma unroll
  for (int m = 1; m <= 16; m <<= 1) {
    acc0 += swz_xor(acc0, m);
    acc1 += swz_xor(acc1, m);
  }
  acc0 += __shfl_xor(acc0, 32, 64);
  acc1 += __shfl_xor(acc1, 32, 64);
  if (l == 0) {
    outP[(size_t)b * ND + d0 + wv * 2 + 0] = acc0;
    outP[(size_t)b * ND + d0 + wv * 2 + 1] = acc1;
  }
}

extern "C" void kernel_launch(void* const* d_in, const int* in_sizes, int n_in,
                              void* d_out, int out_size, void* d_ws, size_t ws_size,
                              hipStream_t stream) {
  const float* feat    = (const float*)d_in[0];
  const int*   lengths = (const int*)d_in[1];
  const float* kF      = (const float*)d_in[2];
  const float* rkF     = (const float*)d_in[3];
  const float* bF      = (const float*)d_in[4];
  const float* kB      = (const float*)d_in[5];
  const float* rkB     = (const float*)d_in[6];
  const float* bB      = (const float*)d_in[7];
  const float* lw      = (const float*)d_in[8];

  float* outP = (float*)d_out;                 // pooled [64,1024]
  float* outW = (float*)d_out + NB * ND;       // weights [64,512]

  float* ws     = (float*)d_ws;
  float* xproj  = ws;                          // [2][512][96]
  float* scoreW = ws + 2 * KK * G3;            // [2][64][512]
  float* wts    = scoreW + 2 * NB * KK;        // [64][512]

  xproj_kernel<<<KK, 192, 0, stream>>>(kF, bF, kB, bB, xproj);
  gru5_kernel<<<NB * 2, 64, 0, stream>>>(rkF, rkB, bF, bB, lw, lengths, xproj, scoreW);
  softmax_kernel<<<NB, 256, 0, stream>>>(lengths, scoreW, wts, outW);
  sortpool_kernel<<<NB * 64, 512, 0, stream>>>(feat, lengths, wts, outP);
}

// Round 9
// 236.087 us; speedup vs baseline: 1.4663x; 1.1267x over previous
//
#include <hip/hip_runtime.h>
#include <math.h>

#define NB 64
#define KK 512
#define ND 1024
#define NH 32
#define G3 96   // 3*H
#define DPE 32

typedef float v2f __attribute__((ext_vector_type(2)));

// xor-shuffle across lanes: ds_swizzle (imm pattern), masks 1..16.
__device__ __forceinline__ float swz_xor(float x, const int m) {
  int xi = __float_as_int(x), r;
  if (m == 1)       r = __builtin_amdgcn_ds_swizzle(xi, 0x041F);
  else if (m == 2)  r = __builtin_amdgcn_ds_swizzle(xi, 0x081F);
  else if (m == 4)  r = __builtin_amdgcn_ds_swizzle(xi, 0x101F);
  else if (m == 8)  r = __builtin_amdgcn_ds_swizzle(xi, 0x201F);
  else              r = __builtin_amdgcn_ds_swizzle(xi, 0x401F);  // m == 16
  return __int_as_float(r);
}

__device__ __forceinline__ float rdl(float v, int i) {
  return __uint_as_float(__builtin_amdgcn_readlane(__float_as_uint(v), i));
}

// ---------------- kernel 1: x-projection (pe @ kernel + bias0 + zr-part of
// bias1 folded), both dirs ----------------------------------------------------
__global__ __launch_bounds__(192) void xproj_kernel(
    const float* __restrict__ kF, const float* __restrict__ bF,
    const float* __restrict__ kB, const float* __restrict__ bB,
    float* __restrict__ xproj) {
  int k = blockIdx.x;
  int t = threadIdx.x;
  __shared__ float pe[DPE];
  if (t < DPE) {
    int j = t >> 1;
    float dv = expf((float)j * -0.57564627324851147f);  // -ln(10000)/16
    float arg = (float)k * dv;
    pe[t] = (t & 1) ? cosf(arg) : sinf(arg);
  }
  __syncthreads();
  int dir = t / G3;
  int c = t - dir * G3;
  const float* kern = dir ? kB : kF;
  const float* bias = dir ? bB : bF;
  float acc = bias[c] + (c < 64 ? bias[G3 + c] : 0.f);  // fold recurrent zr bias
#pragma unroll
  for (int i = 0; i < DPE; ++i) acc = fmaf(pe[i], kern[i * G3 + c], acc);
  xproj[dir * (KK * G3) + k * G3 + c] = acc;
}

// ---------------- kernel 2: sequential GRU, 1 wave per (b,dir) --------------
// Issue-bound (R6 A/B proved it): minimize per-step instructions. Straight-line
// 8-step main body (no per-step guards), guarded tail for len%8.
#if __has_builtin(__builtin_amdgcn_permlane32_swap)
#define PLSWAP(sig, z, r) { auto pr_ = __builtin_amdgcn_permlane32_swap(       \
      __float_as_uint(sig), __float_as_uint(sig), false, false);               \
    z = __uint_as_float(pr_[0]); r = __uint_as_float(pr_[1]); }
#else
#define PLSWAP(sig, z, r) { float o_ = __shfl_xor(sig, 32, 64);                \
    bool mz_ = (zrcol < 32); z = mz_ ? sig : o_; r = mz_ ? o_ : sig; }
#endif

#define GRU_STEP8(S, J)                                                        \
  do {                                                                         \
    float hs[32];                                                              \
    _Pragma("unroll")                                                          \
    for (int i = 0; i < 32; ++i) hs[i] = rdl(hval, i);                         \
    v2f a0 = {0.f, 0.f}, a1 = {0.f, 0.f}, a2 = {0.f, 0.f}, a3 = {0.f, 0.f};    \
    _Pragma("unroll")                                                          \
    for (int i = 0; i < 32; i += 4) {                                          \
      a0 = __builtin_elementwise_fma((v2f){hs[i+0], hs[i+0]}, rk2[i+0], a0);   \
      a1 = __builtin_elementwise_fma((v2f){hs[i+1], hs[i+1]}, rk2[i+1], a1);   \
      a2 = __builtin_elementwise_fma((v2f){hs[i+2], hs[i+2]}, rk2[i+2], a2);   \
      a3 = __builtin_elementwise_fma((v2f){hs[i+3], hs[i+3]}, rk2[i+3], a3);   \
    }                                                                          \
    v2f asum = (a0 + a1) + (a2 + a3);                                          \
    float zr_pre = asum.x + xzr[J];                                            \
    float hh = asum.y + b_h;                                                   \
    float sig = __builtin_amdgcn_rcpf(1.f + __expf(-zr_pre));                  \
    float z, r;                                                                \
    PLSWAP(sig, z, r);                                                         \
    float pre = fmaf(r, hh, xh[J]);                                            \
    float e2 = __expf(2.f * pre);                                              \
    float hc = fmaf(-2.f, __builtin_amdgcn_rcpf(e2 + 1.f), 1.f);               \
    hval = fmaf(z, hval - hc, hc);                                             \
    int p = dir ? (len - 1 - (S)) : (S);                                       \
    if (l < 32) hist[p * NH + (c ^ (p & 31))] = hval;                          \
    int pn = (S) + 8; pn = pn > len - 1 ? len - 1 : pn;                        \
    const float* rp = xp_g + (size_t)(dir ? (len - 1 - pn) : pn) * G3;         \
    xzr[J] = rp[zrcol];                                                        \
    xh[J] = rp[64 + c];                                                        \
  } while (0)

__global__ __launch_bounds__(64, 1) void gru5_kernel(
    const float* __restrict__ rkF, const float* __restrict__ rkB,
    const float* __restrict__ bF, const float* __restrict__ bB,
    const float* __restrict__ lw, const int* __restrict__ lengths,
    const float* __restrict__ xproj, float* __restrict__ scoreW) {
  __shared__ float hist[KK * NH];  // 64 KB, element (k,c) at k*32 + (c^(k&31))
  int bid = blockIdx.x;
  int b = bid >> 1, dir = bid & 1;
  int l = threadIdx.x;
  int c = l & 31;
  const float* rk_g = dir ? rkB : rkF;
  const float* bias = dir ? bB : bF;
  const float* xp_g = xproj + dir * (KK * G3);
  int len = lengths[b];

#if __has_builtin(__builtin_amdgcn_permlane32_swap)
  auto chk = __builtin_amdgcn_permlane32_swap(
      __float_as_uint(l < 32 ? 1.f : 2.f), __float_as_uint(l < 32 ? 1.f : 2.f),
      false, false);
  bool xIsLo = (__uint_as_float(chk[0]) == 1.f);
#else
  bool xIsLo = true;
#endif
  // Column assignment so that swap-result[0] is always z, result[1] always r.
  int zrcol = (xIsLo == (l < 32)) ? c : (32 + c);

  v2f rk2[32];  // .x: zr-column coefficient, .y: h-column coefficient
#pragma unroll
  for (int i = 0; i < 32; ++i) {
    rk2[i] = (v2f){rk_g[i * G3 + zrcol], rk_g[i * G3 + 64 + c]};
  }
  float b_h = bias[G3 + 64 + c];

  // prefetch ring, depth 8 (static indices via full unroll)
  float xzr[8], xh[8];
#pragma unroll
  for (int j = 0; j < 8; ++j) {
    int pn = dir ? (len - 1 - j) : j;
    const float* rp = xp_g + (size_t)pn * G3;
    xzr[j] = rp[zrcol];
    xh[j] = rp[64 + c];
  }

  float hval = 0.f;
  int s0 = 0;
  for (; s0 + 8 <= len; s0 += 8) {
#pragma unroll
    for (int j = 0; j < 8; ++j) GRU_STEP8(s0 + j, j);
  }
  if (s0 < len) {
#pragma unroll
    for (int j = 0; j < 8; ++j) {
      if (s0 + j < len) GRU_STEP8(s0 + j, j);
    }
  }
  __syncthreads();

  // tail: scores for all k in parallel (lane l handles k = it*64 + l)
  float lws[NH];
#pragma unroll
  for (int i = 0; i < NH; ++i) lws[i] = lw[dir * NH + i];
  float* so = scoreW + (size_t)(dir * NB + b) * KK;
#pragma unroll
  for (int it = 0; it < 8; ++it) {
    int k = it * 64 + l;
    if (k < len) {
      float acc = 0.f;
#pragma unroll
      for (int i = 0; i < NH; ++i)
        acc = fmaf(hist[k * NH + (i ^ (k & 31))], lws[i], acc);
      so[k] = acc;
    }
  }
}

// ---------------- kernel 3: softmax over K per batch ------------------------
__global__ __launch_bounds__(256) void softmax_kernel(
    const int* __restrict__ lengths, const float* __restrict__ scoreW,
    float* __restrict__ wts, float* __restrict__ outW) {
  int b = blockIdx.x;
  int t = threadIdx.x;
  int len = lengths[b];
  const float* sf = scoreW + b * KK;
  const float* sb = scoreW + (NB + b) * KK;
  int k0 = t, k1 = t + 256;
  float s0 = -10000.f, s1 = -10000.f;
  if (k0 < len) s0 = sf[k0] + sb[k0];
  if (k1 < len) s1 = sf[k1] + sb[k1];
  float mx = fmaxf(s0, s1);
#pragma unroll
  for (int m = 32; m >= 1; m >>= 1) mx = fmaxf(mx, __shfl_xor(mx, m, 64));
  __shared__ float redm[4];
  __shared__ float reds[4];
  int wid = t >> 6, lane = t & 63;
  if (lane == 0) redm[wid] = mx;
  __syncthreads();
  mx = fmaxf(fmaxf(redm[0], redm[1]), fmaxf(redm[2], redm[3]));
  float e0 = expf((s0 - mx) * 10.f);  // padded -> exp(~-1e5) == 0 exactly
  float e1 = expf((s1 - mx) * 10.f);
  float sum = e0 + e1;
#pragma unroll
  for (int m = 32; m >= 1; m >>= 1) sum += __shfl_xor(sum, m, 64);
  if (lane == 0) reds[wid] = sum;
  __syncthreads();
  sum = (reds[0] + reds[1]) + (reds[2] + reds[3]);
  float inv = 1.f / sum;
  float w0 = e0 * inv, w1 = e1 * inv;
  wts[b * KK + k0] = w0;
  wts[b * KK + k1] = w1;
  outW[b * KK + k0] = w0;
  outW[b * KK + k1] = w1;
}

// ---------------- kernel 4: per-(b,d) descending sort + weighted pool -------
// R=32 layout: column = 16 lanes x 32 regs, s = 32*(l&15) + r. 256 threads =
// 4 waves x 4 col-groups = exactly the 16 columns of this tile (R8 bug: 512
// threads covered 32 cols and wrote past the tile). Cross-lane substages
// 21 -> 10 per column vs R=8; in-reg CE = min+max (no selects).
#define CEA(a, b) { float lo_ = fminf(a, b), hi_ = fmaxf(a, b); a = lo_; b = hi_; }
#define CED(a, b) { float lo_ = fminf(a, b), hi_ = fmaxf(a, b); a = hi_; b = lo_; }
#define XORALL(MASK)                                                           \
  _Pragma("unroll")                                                            \
  for (int r_ = 0; r_ < 32; ++r_)                                              \
    v[r_] = __int_as_float(__float_as_int(v[r_]) ^ (MASK));
#define INREG_ASC(J)                                                           \
  {                                                                            \
    const int m_ = 1 << (J);                                                   \
    _Pragma("unroll")                                                          \
    for (int r_ = 0; r_ < 32; ++r_)                                            \
      if (!(r_ & m_)) CEA(v[r_], v[r_ | m_]);                                  \
  }
#define CROSS(MLANE, HB)                                                       \
  {                                                                            \
    bool hb_ = (HB);                                                           \
    _Pragma("unroll")                                                          \
    for (int r_ = 0; r_ < 32; ++r_) {                                          \
      float p_ = swz_xor(v[r_], (MLANE));                                      \
      float mn_ = fminf(v[r_], p_), mx_ = fmaxf(v[r_], p_);                    \
      v[r_] = hb_ ? mx_ : mn_;                                                 \
    }                                                                          \
  }

__global__ __launch_bounds__(256, 4) void sortpool_kernel(
    const float* __restrict__ feat, const int* __restrict__ lengths,
    const float* __restrict__ wts, float* __restrict__ outP) {
  __shared__ float tile[KK * 16];   // 32 KB, rotation-swizzled
  __shared__ float wperm[KK];       // w[j] at (j&31)*16 + (j>>5)
  int bid = blockIdx.x;
  int b = bid >> 6;
  int dt = bid & 63;
  int d0 = dt * 16;
  int t = threadIdx.x;
  int len = lengths[b];

#pragma unroll
  for (int it = 0; it < 2; ++it) {
    int i = it * 256 + t;
    wperm[(i & 31) * 16 + (i >> 5)] = wts[b * KK + i];
  }

  // stage features: 64B-aligned float4 reads, rotation-swizzled LDS writes
  const float4* g = reinterpret_cast<const float4*>(feat + (size_t)b * KK * ND + d0);
  int c4 = t & 3, kb = t >> 2;   // kb in 0..63
#pragma unroll
  for (int it = 0; it < 8; ++it) {
    int k = it * 64 + kb;
    float4 vv = g[(size_t)k * 256 + c4];
    if (k >= len) { vv.x = -10000.f; vv.y = -10000.f; vv.z = -10000.f; vv.w = -10000.f; }
    int base = k * 16;
    int rot = (k >> 3) + (k >> 7) + (k & 7);
    tile[base + ((c4 * 4 + 0 + rot) & 15)] = vv.x;
    tile[base + ((c4 * 4 + 1 + rot) & 15)] = vv.y;
    tile[base + ((c4 * 4 + 2 + rot) & 15)] = vv.z;
    tile[base + ((c4 * 4 + 3 + rot) & 15)] = vv.w;
  }
  __syncthreads();

  int wv = t >> 6, l = t & 63;
  int i = l & 15;                // element-group index (s bits 5..8)
  int dloc = wv * 4 + (l >> 4);  // column within tile, 0..15
  float v[32];
#pragma unroll
  for (int r = 0; r < 32; ++r) {
    int k = 32 * i + r;
    int rot = (k >> 3) + (k >> 7) + (k & 7);
    v[r] = tile[k * 16 + ((dloc + rot) & 15)];
  }

  // ---- stages kk=1..4: fully in-reg, compile-time directions (r bits) ----
#pragma unroll
  for (int kk = 1; kk <= 4; ++kk) {
#pragma unroll
    for (int j = kk - 1; j >= 0; --j) {
      const int m = 1 << j;
#pragma unroll
      for (int r = 0; r < 32; ++r) {
        if (!(r & m)) {
          if (((r >> kk) & 1) == 0) { CEA(v[r], v[r | m]); }
          else                      { CED(v[r], v[r | m]); }
        }
      }
    }
  }

  const int dm5 = (l & 1) << 31;
  const int dm6 = ((l >> 1) & 1) << 31;
  const int dm7 = ((l >> 2) & 1) << 31;
  const int dm8 = ((l >> 3) & 1) << 31;

  // ---- kk=5: dir = lane bit0; all substages in-reg ----
  XORALL(dm5);
  INREG_ASC(4) INREG_ASC(3) INREG_ASC(2) INREG_ASC(1) INREG_ASC(0)
  // ---- kk=6 ----
  XORALL(dm5 ^ dm6);
  CROSS(1, l & 1)
  INREG_ASC(4) INREG_ASC(3) INREG_ASC(2) INREG_ASC(1) INREG_ASC(0)
  // ---- kk=7 ----
  XORALL(dm6 ^ dm7);
  CROSS(2, (l >> 1) & 1)
  CROSS(1, l & 1)
  INREG_ASC(4) INREG_ASC(3) INREG_ASC(2) INREG_ASC(1) INREG_ASC(0)
  // ---- kk=8 ----
  XORALL(dm7 ^ dm8);
  CROSS(4, (l >> 2) & 1)
  CROSS(2, (l >> 1) & 1)
  CROSS(1, l & 1)
  INREG_ASC(4) INREG_ASC(3) INREG_ASC(2) INREG_ASC(1) INREG_ASC(0)
  // ---- kk=9: dir = 0 -> back to plain domain ----
  XORALL(dm8);
  CROSS(8, (l >> 3) & 1)
  CROSS(4, (l >> 2) & 1)
  CROSS(2, (l >> 1) & 1)
  CROSS(1, l & 1)
  INREG_ASC(4) INREG_ASC(3) INREG_ASC(2) INREG_ASC(1) INREG_ASC(0)
  // ascending in s = 32*i + r; descending rank jd = 511 - s.

  // weighted sum: w[jd], jd&31 = 31-r (const per reg), jd>>5 = 15-i (per lane).
  // wts[jd] == 0 exactly for jd >= len, so no guard needed.
  float acc = 0.f;
#pragma unroll
  for (int r = 0; r < 32; ++r) {
    float w = wperm[(31 - r) * 16 + (15 - i)];
    acc = fmaf(v[r], w, acc);
  }
  acc += swz_xor(acc, 1);
  acc += swz_xor(acc, 2);
  acc += swz_xor(acc, 4);
  acc += swz_xor(acc, 8);
  if (i == 0) outP[(size_t)b * ND + d0 + dloc] = acc;
}

extern "C" void kernel_launch(void* const* d_in, const int* in_sizes, int n_in,
                              void* d_out, int out_size, void* d_ws, size_t ws_size,
                              hipStream_t stream) {
  const float* feat    = (const float*)d_in[0];
  const int*   lengths = (const int*)d_in[1];
  const float* kF      = (const float*)d_in[2];
  const float* rkF     = (const float*)d_in[3];
  const float* bF      = (const float*)d_in[4];
  const float* kB      = (const float*)d_in[5];
  const float* rkB     = (const float*)d_in[6];
  const float* bB      = (const float*)d_in[7];
  const float* lw      = (const float*)d_in[8];

  float* outP = (float*)d_out;                 // pooled [64,1024]
  float* outW = (float*)d_out + NB * ND;       // weights [64,512]

  float* ws     = (float*)d_ws;
  float* xproj  = ws;                          // [2][512][96]
  float* scoreW = ws + 2 * KK * G3;            // [2][64][512]
  float* wts    = scoreW + 2 * NB * KK;        // [64][512]

  xproj_kernel<<<KK, 192, 0, stream>>>(kF, bF, kB, bB, xproj);
  gru5_kernel<<<NB * 2, 64, 0, stream>>>(rkF, rkB, bF, bB, lw, lengths, xproj, scoreW);
  softmax_kernel<<<NB, 256, 0, stream>>>(lengths, scoreW, wts, outW);
  sortpool_kernel<<<NB * 64, 256, 0, stream>>>(feat, lengths, wts, outP);
}

// Round 10
// 174.807 us; speedup vs baseline: 1.9803x; 1.3506x over previous
//
#include <hip/hip_runtime.h>
#include <math.h>

#define NB 64
#define KK 512
#define ND 1024
#define NH 32
#define G3 96   // 3*H
#define DPE 32

typedef float v2f __attribute__((ext_vector_type(2)));

// xor-shuffle across lanes: ds_swizzle (imm pattern), masks 1..16.
__device__ __forceinline__ float swz_xor(float x, const int m) {
  int xi = __float_as_int(x), r;
  if (m == 1)       r = __builtin_amdgcn_ds_swizzle(xi, 0x041F);
  else if (m == 2)  r = __builtin_amdgcn_ds_swizzle(xi, 0x081F);
  else if (m == 4)  r = __builtin_amdgcn_ds_swizzle(xi, 0x101F);
  else if (m == 8)  r = __builtin_amdgcn_ds_swizzle(xi, 0x201F);
  else              r = __builtin_amdgcn_ds_swizzle(xi, 0x401F);  // m == 16
  return __int_as_float(r);
}

__device__ __forceinline__ float rdl(float v, int i) {
  return __uint_as_float(__builtin_amdgcn_readlane(__float_as_uint(v), i));
}

#if __has_builtin(__builtin_amdgcn_permlane32_swap)
#define PLSWAP(sig, z, r) { auto pr_ = __builtin_amdgcn_permlane32_swap(       \
      __float_as_uint(sig), __float_as_uint(sig), false, false);               \
    z = __uint_as_float(pr_[0]); r = __uint_as_float(pr_[1]); }
#else
#define PLSWAP(sig, z, r) { float o_ = __shfl_xor(sig, 32, 64);                \
    bool mz_ = (zrcol < 32); z = mz_ ? sig : o_; r = mz_ ? o_ : sig; }
#endif

// ---------------- kernel 1: x-projection --------------------------------------
__global__ __launch_bounds__(192) void xproj_kernel(
    const float* __restrict__ kF, const float* __restrict__ bF,
    const float* __restrict__ kB, const float* __restrict__ bB,
    float* __restrict__ xproj) {
  int k = blockIdx.x;
  int t = threadIdx.x;
  __shared__ float pe[DPE];
  if (t < DPE) {
    int j = t >> 1;
    float dv = expf((float)j * -0.57564627324851147f);  // -ln(10000)/16
    float arg = (float)k * dv;
    pe[t] = (t & 1) ? cosf(arg) : sinf(arg);
  }
  __syncthreads();
  int dir = t / G3;
  int c = t - dir * G3;
  const float* kern = dir ? kB : kF;
  const float* bias = dir ? bB : bF;
  float acc = bias[c] + (c < 64 ? bias[G3 + c] : 0.f);  // fold recurrent zr bias
#pragma unroll
  for (int i = 0; i < DPE; ++i) acc = fmaf(pe[i], kern[i * G3 + c], acc);
  xproj[dir * (KK * G3) + k * G3 + c] = acc;
}

// ================= GRU core step (shared by both variants) ===================
// STOREH is an expression storing hval for sequence position p.
#define GRU_STEP_CORE(S, J, STOREH)                                            \
  do {                                                                         \
    float hs[32];                                                              \
    _Pragma("unroll")                                                          \
    for (int i = 0; i < 32; ++i) hs[i] = rdl(hval, i);                         \
    v2f a0 = {0.f, 0.f}, a1 = {0.f, 0.f}, a2 = {0.f, 0.f}, a3 = {0.f, 0.f};    \
    _Pragma("unroll")                                                          \
    for (int i = 0; i < 32; i += 4) {                                          \
      a0 = __builtin_elementwise_fma((v2f){hs[i+0], hs[i+0]}, rk2[i+0], a0);   \
      a1 = __builtin_elementwise_fma((v2f){hs[i+1], hs[i+1]}, rk2[i+1], a1);   \
      a2 = __builtin_elementwise_fma((v2f){hs[i+2], hs[i+2]}, rk2[i+2], a2);   \
      a3 = __builtin_elementwise_fma((v2f){hs[i+3], hs[i+3]}, rk2[i+3], a3);   \
    }                                                                          \
    v2f asum = (a0 + a1) + (a2 + a3);                                          \
    float zr_pre = asum.x + xzr[J];                                            \
    float hh = asum.y + b_h;                                                   \
    float sig = __builtin_amdgcn_rcpf(1.f + __expf(-zr_pre));                  \
    float z, r;                                                                \
    PLSWAP(sig, z, r);                                                         \
    float pre = fmaf(r, hh, xh[J]);                                            \
    float e2 = __expf(2.f * pre);                                              \
    float hc = fmaf(-2.f, __builtin_amdgcn_rcpf(e2 + 1.f), 1.f);               \
    hval = fmaf(z, hval - hc, hc);                                             \
    int p = dir ? (len - 1 - (S)) : (S);                                       \
    if (l < 32) { STOREH; }                                                    \
    int pn = (S) + 8; pn = pn > len - 1 ? len - 1 : pn;                        \
    const float* rp = xp_g + (size_t)(dir ? (len - 1 - pn) : pn) * G3;         \
    xzr[J] = rp[zrcol];                                                        \
    xh[J] = rp[64 + c];                                                        \
  } while (0)

// ---------------- fallback kernel 2: gru5 (R9 verbatim behavior) ------------
__global__ __launch_bounds__(64, 1) void gru5_kernel(
    const float* __restrict__ rkF, const float* __restrict__ rkB,
    const float* __restrict__ bF, const float* __restrict__ bB,
    const float* __restrict__ lw, const int* __restrict__ lengths,
    const float* __restrict__ xproj, float* __restrict__ scoreW) {
  __shared__ float hist[KK * NH];  // 64 KB, element (k,c) at k*32 + (c^(k&31))
  int bid = blockIdx.x;
  int b = bid >> 1, dir = bid & 1;
  int l = threadIdx.x;
  int c = l & 31;
  const float* rk_g = dir ? rkB : rkF;
  const float* bias = dir ? bB : bF;
  const float* xp_g = xproj + dir * (KK * G3);
  int len = lengths[b];

#if __has_builtin(__builtin_amdgcn_permlane32_swap)
  auto chk = __builtin_amdgcn_permlane32_swap(
      __float_as_uint(l < 32 ? 1.f : 2.f), __float_as_uint(l < 32 ? 1.f : 2.f),
      false, false);
  bool xIsLo = (__uint_as_float(chk[0]) == 1.f);
#else
  bool xIsLo = true;
#endif
  int zrcol = (xIsLo == (l < 32)) ? c : (32 + c);

  v2f rk2[32];
#pragma unroll
  for (int i = 0; i < 32; ++i)
    rk2[i] = (v2f){rk_g[i * G3 + zrcol], rk_g[i * G3 + 64 + c]};
  float b_h = bias[G3 + 64 + c];

  float xzr[8], xh[8];
#pragma unroll
  for (int j = 0; j < 8; ++j) {
    int pn = dir ? (len - 1 - j) : j;
    const float* rp = xp_g + (size_t)pn * G3;
    xzr[j] = rp[zrcol];
    xh[j] = rp[64 + c];
  }

  float hval = 0.f;
  int s0 = 0;
  for (; s0 + 8 <= len; s0 += 8) {
#pragma unroll
    for (int j = 0; j < 8; ++j)
      GRU_STEP_CORE(s0 + j, j, hist[p * NH + (c ^ (p & 31))] = hval);
  }
  if (s0 < len) {
#pragma unroll
    for (int j = 0; j < 8; ++j) {
      if (s0 + j < len)
        GRU_STEP_CORE(s0 + j, j, hist[p * NH + (c ^ (p & 31))] = hval);
    }
  }
  __syncthreads();

  float lws[NH];
#pragma unroll
  for (int i = 0; i < NH; ++i) lws[i] = lw[dir * NH + i];
  float* so = scoreW + (size_t)(dir * NB + b) * KK;
#pragma unroll
  for (int it = 0; it < 8; ++it) {
    int k = it * 64 + l;
    if (k < len) {
      float acc = 0.f;
#pragma unroll
      for (int i = 0; i < NH; ++i)
        acc = fmaf(hist[k * NH + (i ^ (k & 31))], lws[i], acc);
      so[k] = acc;
    }
  }
}

// ---------------- fallback kernel 3: softmax from scoreW --------------------
__global__ __launch_bounds__(256) void softmax_kernel(
    const int* __restrict__ lengths, const float* __restrict__ scoreW,
    float* __restrict__ wts, float* __restrict__ outW) {
  int b = blockIdx.x;
  int t = threadIdx.x;
  int len = lengths[b];
  const float* sf = scoreW + b * KK;
  const float* sb = scoreW + (NB + b) * KK;
  int k0 = t, k1 = t + 256;
  float s0 = -10000.f, s1 = -10000.f;
  if (k0 < len) s0 = sf[k0] + sb[k0];
  if (k1 < len) s1 = sf[k1] + sb[k1];
  float mx = fmaxf(s0, s1);
#pragma unroll
  for (int m = 32; m >= 1; m >>= 1) mx = fmaxf(mx, __shfl_xor(mx, m, 64));
  __shared__ float redm[4];
  __shared__ float reds[4];
  int wid = t >> 6, lane = t & 63;
  if (lane == 0) redm[wid] = mx;
  __syncthreads();
  mx = fmaxf(fmaxf(redm[0], redm[1]), fmaxf(redm[2], redm[3]));
  float e0 = expf((s0 - mx) * 10.f);
  float e1 = expf((s1 - mx) * 10.f);
  float sum = e0 + e1;
#pragma unroll
  for (int m = 32; m >= 1; m >>= 1) sum += __shfl_xor(sum, m, 64);
  if (lane == 0) reds[wid] = sum;
  __syncthreads();
  sum = (reds[0] + reds[1]) + (reds[2] + reds[3]);
  float inv = 1.f / sum;
  float w0 = e0 * inv, w1 = e1 * inv;
  wts[b * KK + k0] = w0;
  wts[b * KK + k1] = w1;
  outW[b * KK + k0] = w0;
  outW[b * KK + k1] = w1;
}

// ================= R=32 bitonic sort machinery ===============================
#define CEA(a, b) { float lo_ = fminf(a, b), hi_ = fmaxf(a, b); a = lo_; b = hi_; }
#define CED(a, b) { float lo_ = fminf(a, b), hi_ = fmaxf(a, b); a = hi_; b = lo_; }
#define XORALL(MASK)                                                           \
  _Pragma("unroll")                                                            \
  for (int r_ = 0; r_ < 32; ++r_)                                              \
    v[r_] = __int_as_float(__float_as_int(v[r_]) ^ (MASK));
#define INREG_ASC(J)                                                           \
  {                                                                            \
    const int m_ = 1 << (J);                                                   \
    _Pragma("unroll")                                                          \
    for (int r_ = 0; r_ < 32; ++r_)                                            \
      if (!(r_ & m_)) CEA(v[r_], v[r_ | m_]);                                  \
  }
#define CROSS(MLANE, HB)                                                       \
  {                                                                            \
    bool hb_ = (HB);                                                           \
    _Pragma("unroll")                                                          \
    for (int r_ = 0; r_ < 32; ++r_) {                                          \
      float p_ = swz_xor(v[r_], (MLANE));                                      \
      float mn_ = fminf(v[r_], p_), mx_ = fmaxf(v[r_], p_);                    \
      v[r_] = hb_ ? mx_ : mn_;                                                 \
    }                                                                          \
  }

// Full 512-sort on v[32] (s = 32*i + r ascending), i = lane&15.
#define SORT512(l_)                                                            \
  _Pragma("unroll")                                                            \
  for (int kk = 1; kk <= 4; ++kk) {                                            \
    _Pragma("unroll")                                                          \
    for (int j = kk - 1; j >= 0; --j) {                                        \
      const int m = 1 << j;                                                    \
      _Pragma("unroll")                                                        \
      for (int r = 0; r < 32; ++r) {                                           \
        if (!(r & m)) {                                                        \
          if (((r >> kk) & 1) == 0) { CEA(v[r], v[r | m]); }                   \
          else                      { CED(v[r], v[r | m]); }                   \
        }                                                                      \
      }                                                                        \
    }                                                                          \
  }                                                                            \
  {                                                                            \
    const int dm5 = ((l_) & 1) << 31;                                          \
    const int dm6 = (((l_) >> 1) & 1) << 31;                                   \
    const int dm7 = (((l_) >> 2) & 1) << 31;                                   \
    const int dm8 = (((l_) >> 3) & 1) << 31;                                   \
    XORALL(dm5);                                                               \
    INREG_ASC(4) INREG_ASC(3) INREG_ASC(2) INREG_ASC(1) INREG_ASC(0)           \
    XORALL(dm5 ^ dm6);                                                         \
    CROSS(1, (l_) & 1)                                                         \
    INREG_ASC(4) INREG_ASC(3) INREG_ASC(2) INREG_ASC(1) INREG_ASC(0)           \
    XORALL(dm6 ^ dm7);                                                         \
    CROSS(2, ((l_) >> 1) & 1)                                                  \
    CROSS(1, (l_) & 1)                                                         \
    INREG_ASC(4) INREG_ASC(3) INREG_ASC(2) INREG_ASC(1) INREG_ASC(0)           \
    XORALL(dm7 ^ dm8);                                                         \
    CROSS(4, ((l_) >> 2) & 1)                                                  \
    CROSS(2, ((l_) >> 1) & 1)                                                  \
    CROSS(1, (l_) & 1)                                                         \
    INREG_ASC(4) INREG_ASC(3) INREG_ASC(2) INREG_ASC(1) INREG_ASC(0)           \
    XORALL(dm8);                                                               \
    CROSS(8, ((l_) >> 3) & 1)                                                  \
    CROSS(4, ((l_) >> 2) & 1)                                                  \
    CROSS(2, ((l_) >> 1) & 1)                                                  \
    CROSS(1, (l_) & 1)                                                         \
    INREG_ASC(4) INREG_ASC(3) INREG_ASC(2) INREG_ASC(1) INREG_ASC(0)           \
  }

// ---------------- fallback kernel 4: sortpool (R9 verbatim) -----------------
__global__ __launch_bounds__(256, 4) void sortpool_kernel(
    const float* __restrict__ feat, const int* __restrict__ lengths,
    const float* __restrict__ wts, float* __restrict__ outP) {
  __shared__ float tile[KK * 16];
  __shared__ float wperm[KK];
  int bid = blockIdx.x;
  int b = bid >> 6;
  int dt = bid & 63;
  int d0 = dt * 16;
  int t = threadIdx.x;
  int len = lengths[b];

#pragma unroll
  for (int it = 0; it < 2; ++it) {
    int i = it * 256 + t;
    wperm[(i & 31) * 16 + (i >> 5)] = wts[b * KK + i];
  }
  const float4* g = reinterpret_cast<const float4*>(feat + (size_t)b * KK * ND + d0);
  int c4 = t & 3, kb = t >> 2;
#pragma unroll
  for (int it = 0; it < 8; ++it) {
    int k = it * 64 + kb;
    float4 vv = g[(size_t)k * 256 + c4];
    if (k >= len) { vv.x = -10000.f; vv.y = -10000.f; vv.z = -10000.f; vv.w = -10000.f; }
    int base = k * 16;
    int rot = (k >> 3) + (k >> 7) + (k & 7);
    tile[base + ((c4 * 4 + 0 + rot) & 15)] = vv.x;
    tile[base + ((c4 * 4 + 1 + rot) & 15)] = vv.y;
    tile[base + ((c4 * 4 + 2 + rot) & 15)] = vv.z;
    tile[base + ((c4 * 4 + 3 + rot) & 15)] = vv.w;
  }
  __syncthreads();

  int wv = t >> 6, l = t & 63;
  int i = l & 15;
  int dloc = wv * 4 + (l >> 4);
  float v[32];
#pragma unroll
  for (int r = 0; r < 32; ++r) {
    int k = 32 * i + r;
    int rot = (k >> 3) + (k >> 7) + (k & 7);
    v[r] = tile[k * 16 + ((dloc + rot) & 15)];
  }

  SORT512(l)

  float acc = 0.f;
#pragma unroll
  for (int r = 0; r < 32; ++r) {
    float w = wperm[(31 - r) * 16 + (15 - i)];
    acc = fmaf(v[r], w, acc);
  }
  acc += swz_xor(acc, 1);
  acc += swz_xor(acc, 2);
  acc += swz_xor(acc, 4);
  acc += swz_xor(acc, 8);
  if (i == 0) outP[(size_t)b * ND + d0 + dloc] = acc;
}

// ================= FUSED PATH =================================================
// Blocks 0..127: GRU role (wave 0 only, setprio(3), h -> global hbuf).
// Blocks 128..4223: sort role (R=32 sort, spill descending-sorted tile to ws).
__global__ __launch_bounds__(256, 1) void fused_kernel(
    const float* __restrict__ rkF, const float* __restrict__ rkB,
    const float* __restrict__ bF, const float* __restrict__ bB,
    const int* __restrict__ lengths, const float* __restrict__ xproj,
    float* __restrict__ hbuf, const float* __restrict__ feat,
    float* __restrict__ sortedWS) {
  __shared__ float tile[KK * 16];  // 32 KB (sort role; gru role leaves unused)
  int bid = blockIdx.x;
  int t = threadIdx.x;

  if (bid < 2 * NB) {
    // ---------------- GRU role ----------------
    if (t >= 64) return;  // wave 0 only; no __syncthreads in this role
    __builtin_amdgcn_s_setprio(3);
    int b = bid >> 1, dir = bid & 1;
    int l = t;
    int c = l & 31;
    const float* rk_g = dir ? rkB : rkF;
    const float* bias = dir ? bB : bF;
    const float* xp_g = xproj + dir * (KK * G3);
    int len = lengths[b];

#if __has_builtin(__builtin_amdgcn_permlane32_swap)
    auto chk = __builtin_amdgcn_permlane32_swap(
        __float_as_uint(l < 32 ? 1.f : 2.f), __float_as_uint(l < 32 ? 1.f : 2.f),
        false, false);
    bool xIsLo = (__uint_as_float(chk[0]) == 1.f);
#else
    bool xIsLo = true;
#endif
    int zrcol = (xIsLo == (l < 32)) ? c : (32 + c);

    v2f rk2[32];
#pragma unroll
    for (int i = 0; i < 32; ++i)
      rk2[i] = (v2f){rk_g[i * G3 + zrcol], rk_g[i * G3 + 64 + c]};
    float b_h = bias[G3 + 64 + c];

    float* hb_st = hbuf + (size_t)b * KK * 64 + dir * 32 + c;

    float xzr[8], xh[8];
#pragma unroll
    for (int j = 0; j < 8; ++j) {
      int pn = dir ? (len - 1 - j) : j;
      const float* rp = xp_g + (size_t)pn * G3;
      xzr[j] = rp[zrcol];
      xh[j] = rp[64 + c];
    }

    float hval = 0.f;
    int s0 = 0;
    for (; s0 + 8 <= len; s0 += 8) {
#pragma unroll
      for (int j = 0; j < 8; ++j)
        GRU_STEP_CORE(s0 + j, j, hb_st[(size_t)p * 64] = hval);
    }
    if (s0 < len) {
#pragma unroll
      for (int j = 0; j < 8; ++j) {
        if (s0 + j < len)
          GRU_STEP_CORE(s0 + j, j, hb_st[(size_t)p * 64] = hval);
      }
    }
    return;
  }

  // ---------------- sort role ----------------
  int q = bid - 2 * NB;
  int b = q >> 6;
  int dt = q & 63;
  int d0 = dt * 16;
  int len = lengths[b];

  const float4* g = reinterpret_cast<const float4*>(feat + (size_t)b * KK * ND + d0);
  int c4 = t & 3, kb = t >> 2;
#pragma unroll
  for (int it = 0; it < 8; ++it) {
    int k = it * 64 + kb;
    float4 vv = g[(size_t)k * 256 + c4];
    if (k >= len) { vv.x = -10000.f; vv.y = -10000.f; vv.z = -10000.f; vv.w = -10000.f; }
    int base = k * 16;
    int rot = (k >> 3) + (k >> 7) + (k & 7);
    tile[base + ((c4 * 4 + 0 + rot) & 15)] = vv.x;
    tile[base + ((c4 * 4 + 1 + rot) & 15)] = vv.y;
    tile[base + ((c4 * 4 + 2 + rot) & 15)] = vv.z;
    tile[base + ((c4 * 4 + 3 + rot) & 15)] = vv.w;
  }
  __syncthreads();

  int wv = t >> 6, l = t & 63;
  int i = l & 15;
  int dloc = wv * 4 + (l >> 4);
  float v[32];
#pragma unroll
  for (int r = 0; r < 32; ++r) {
    int k = 32 * i + r;
    int rot = (k >> 3) + (k >> 7) + (k & 7);
    v[r] = tile[k * 16 + ((dloc + rot) & 15)];
  }
  __syncthreads();  // all reads done before any write-back

  SORT512(l)

  // write back descending-sorted values into tile (row jd = 511 - s)
#pragma unroll
  for (int r = 0; r < 32; ++r) {
    int jd = 511 - (32 * i + r);
    int rot = (jd >> 3) + (jd >> 7) + (jd & 7);
    tile[jd * 16 + ((dloc + rot) & 15)] = v[r];
  }
  __syncthreads();

  // coalesced spill: thread t writes rows 2t, 2t+1 (row-major [512][16])
  float4* gout = reinterpret_cast<float4*>(sortedWS + ((size_t)b * 64 + dt) * (KK * 16));
#pragma unroll
  for (int rr = 0; rr < 2; ++rr) {
    int row = 2 * t + rr;
    int rot = (row >> 3) + (row >> 7) + (row & 7);
    float4 o[4];
#pragma unroll
    for (int qq = 0; qq < 4; ++qq) {
      o[qq].x = tile[row * 16 + ((qq * 4 + 0 + rot) & 15)];
      o[qq].y = tile[row * 16 + ((qq * 4 + 1 + rot) & 15)];
      o[qq].z = tile[row * 16 + ((qq * 4 + 2 + rot) & 15)];
      o[qq].w = tile[row * 16 + ((qq * 4 + 3 + rot) & 15)];
      gout[row * 4 + qq] = o[qq];
    }
  }
}

// ---------------- fused kernel 3: score (hbuf . lw) + softmax ---------------
__global__ __launch_bounds__(256) void softscore_kernel(
    const int* __restrict__ lengths, const float* __restrict__ hbuf,
    const float* __restrict__ lw, float* __restrict__ wts,
    float* __restrict__ outW) {
  int b = blockIdx.x;
  int t = threadIdx.x;
  int len = lengths[b];
  __shared__ float lwS[64];
  if (t < 64) lwS[t] = lw[t];
  __syncthreads();
  const float* hb = hbuf + (size_t)b * KK * 64;

  int k0 = t, k1 = t + 256;
  float s0 = -10000.f, s1 = -10000.f;
  if (k0 < len) {
    const float4* h4 = reinterpret_cast<const float4*>(hb + (size_t)k0 * 64);
    float acc = 0.f;
#pragma unroll
    for (int qq = 0; qq < 16; ++qq) {
      float4 vv = h4[qq];
      acc = fmaf(vv.x, lwS[4 * qq + 0], acc);
      acc = fmaf(vv.y, lwS[4 * qq + 1], acc);
      acc = fmaf(vv.z, lwS[4 * qq + 2], acc);
      acc = fmaf(vv.w, lwS[4 * qq + 3], acc);
    }
    s0 = acc;
  }
  if (k1 < len) {
    const float4* h4 = reinterpret_cast<const float4*>(hb + (size_t)k1 * 64);
    float acc = 0.f;
#pragma unroll
    for (int qq = 0; qq < 16; ++qq) {
      float4 vv = h4[qq];
      acc = fmaf(vv.x, lwS[4 * qq + 0], acc);
      acc = fmaf(vv.y, lwS[4 * qq + 1], acc);
      acc = fmaf(vv.z, lwS[4 * qq + 2], acc);
      acc = fmaf(vv.w, lwS[4 * qq + 3], acc);
    }
    s1 = acc;
  }

  float mx = fmaxf(s0, s1);
#pragma unroll
  for (int m = 32; m >= 1; m >>= 1) mx = fmaxf(mx, __shfl_xor(mx, m, 64));
  __shared__ float redm[4];
  __shared__ float reds[4];
  int wid = t >> 6, lane = t & 63;
  if (lane == 0) redm[wid] = mx;
  __syncthreads();
  mx = fmaxf(fmaxf(redm[0], redm[1]), fmaxf(redm[2], redm[3]));
  float e0 = expf((s0 - mx) * 10.f);
  float e1 = expf((s1 - mx) * 10.f);
  float sum = e0 + e1;
#pragma unroll
  for (int m = 32; m >= 1; m >>= 1) sum += __shfl_xor(sum, m, 64);
  if (lane == 0) reds[wid] = sum;
  __syncthreads();
  sum = (reds[0] + reds[1]) + (reds[2] + reds[3]);
  float inv = 1.f / sum;
  float w0 = e0 * inv, w1 = e1 * inv;
  wts[b * KK + k0] = w0;
  wts[b * KK + k1] = w1;
  outW[b * KK + k0] = w0;
  outW[b * KK + k1] = w1;
}

// ---------------- fused kernel 4: weighted sum over spilled sorted tiles ----
__global__ __launch_bounds__(256) void wsum_kernel(
    const float* __restrict__ sortedWS, const float* __restrict__ wts,
    float* __restrict__ outP) {
  int bid = blockIdx.x;
  int b = bid >> 6;
  int dt = bid & 63;
  int t = threadIdx.x;
  __shared__ float wS[KK];
  __shared__ float red[16][17];
  wS[t] = wts[b * KK + t];
  wS[t + 256] = wts[b * KK + t + 256];
  __syncthreads();
  const float* g = sortedWS + ((size_t)b * 64 + dt) * (KK * 16);
  int col = t & 15, rg = t >> 4;
  float acc = 0.f;
#pragma unroll
  for (int m = 0; m < 32; ++m) {
    int row = rg + m * 16;
    acc = fmaf(g[row * 16 + col], wS[row], acc);  // pad rows: w == 0 exactly
  }
  red[rg][col] = acc;
  __syncthreads();
  if (t < 16) {
    float s = 0.f;
#pragma unroll
    for (int m = 0; m < 16; ++m) s += red[m][t];
    outP[(size_t)b * ND + dt * 16 + t] = s;
  }
}

extern "C" void kernel_launch(void* const* d_in, const int* in_sizes, int n_in,
                              void* d_out, int out_size, void* d_ws, size_t ws_size,
                              hipStream_t stream) {
  const float* feat    = (const float*)d_in[0];
  const int*   lengths = (const int*)d_in[1];
  const float* kF      = (const float*)d_in[2];
  const float* rkF     = (const float*)d_in[3];
  const float* bF      = (const float*)d_in[4];
  const float* kB      = (const float*)d_in[5];
  const float* rkB     = (const float*)d_in[6];
  const float* bB      = (const float*)d_in[7];
  const float* lw      = (const float*)d_in[8];

  float* outP = (float*)d_out;                 // pooled [64,1024]
  float* outW = (float*)d_out + NB * ND;       // weights [64,512]

  float* ws = (float*)d_ws;

  // fused-path workspace: xproj | hbuf | wts | sorted
  const size_t oXproj  = 0;
  const size_t oHbuf   = oXproj + 2 * KK * G3;                 //   98304
  const size_t oWts    = oHbuf + (size_t)NB * KK * 64;         // +2097152
  const size_t oSorted = oWts + NB * KK;                       // +  32768
  const size_t needF   = (oSorted + (size_t)NB * ND * KK) * 4; // + 128 MB

  if (ws_size >= needF) {
    float* xproj  = ws + oXproj;
    float* hbuf   = ws + oHbuf;
    float* wts    = ws + oWts;
    float* sorted = ws + oSorted;
    xproj_kernel<<<KK, 192, 0, stream>>>(kF, bF, kB, bB, xproj);
    fused_kernel<<<2 * NB + NB * 64, 256, 0, stream>>>(
        rkF, rkB, bF, bB, lengths, xproj, hbuf, feat, sorted);
    softscore_kernel<<<NB, 256, 0, stream>>>(lengths, hbuf, lw, wts, outW);
    wsum_kernel<<<NB * 64, 256, 0, stream>>>(sorted, wts, outP);
  } else {
    // fallback: R9 serial pipeline (fits in <1 MB of ws)
    float* xproj  = ws;                          // [2][512][96]
    float* scoreW = ws + 2 * KK * G3;            // [2][64][512]
    float* wts    = scoreW + 2 * NB * KK;        // [64][512]
    xproj_kernel<<<KK, 192, 0, stream>>>(kF, bF, kB, bB, xproj);
    gru5_kernel<<<NB * 2, 64, 0, stream>>>(rkF, rkB, bF, bB, lw, lengths, xproj, scoreW);
    softmax_kernel<<<NB, 256, 0, stream>>>(lengths, scoreW, wts, outW);
    sortpool_kernel<<<NB * 64, 256, 0, stream>>>(feat, lengths, wts, outP);
  }
}